// Round 4
// baseline (2212.800 us; speedup 1.0000x reference)
//
#include <hip/hip_runtime.h>
#include <cstdint>

typedef unsigned short u16;
typedef __bf16 bf16x8 __attribute__((ext_vector_type(8)));
typedef float f32x4 __attribute__((ext_vector_type(4)));

#define BNRS 0.9999950000374997f   /* 1/sqrt(1+1e-5) */

__device__ __forceinline__ u16 f2bf(float f) {
  unsigned u = __float_as_uint(f);
  u += 0x7fffu + ((u >> 16) & 1u);
  return (u16)(u >> 16);
}
__device__ __forceinline__ float bf2f(u16 h) {
  return __uint_as_float(((unsigned)h) << 16);
}

// async global->LDS DMA, 16B per lane, dest = wave-uniform base + lane*16
__device__ __forceinline__ void glds16(const u16* g, u16* l) {
  __builtin_amdgcn_global_load_lds(
      (const __attribute__((address_space(1))) void*)g,
      (__attribute__((address_space(3))) void*)l, 16, 0, 0);
}

// ---------------- workspace arena layout (bytes) ----------------
// zeroed every launch:
#define OFF_XN     0ull                     /* [128][81][2048] bf16  42,467,328 */
#define OFF_M1     42467328ull              /* [128][81][1024] bf16  21,233,664 */
#define OFF_M2     63700992ull              /* [128][81][512]  bf16  10,616,832 */
#define SZ_M2      10616832ull
// M2 region reused after mask3 (re-zeroed):
#define OFF_MEANX  63700992ull              /* [8][81][2048] bf16  2,654,208 */
#define OFF_XTN    66355200ull              /* [8][81][2048] bf16  2,654,208 */
#define OFF_TH1    69009408ull              /* [8][81][1024] bf16  1,327,104 */
#define OFF_TC1    70336512ull              /* [8][81][1024] bf16  1,327,104 */
#define OFF_HN     71663616ull              /* [8][81][512]  bf16    663,552 */
#define OFF_CST    72327168ull              /* [392][512]    f32     802,816 */
#define OFF_ZXACC  74317824ull              /* [392][2048] f32     3,211,264 */
#define OFF_ATH1   77529088ull              /* [392][1024] f32     1,605,632 */
#define OFF_ATC1   79134720ull
#define OFF_ATH2   80740352ull              /* [392][512] f32        802,816 */
#define OFF_ATC2   81543168ull
#define OFF_FEA    82345984ull              /* [128] f32 */
#define OFF_W      82346496ull              /* [128] f32 */
#define OFF_OUTS   82347008ull              /* [8][512] f32 */
#define Z0_END     82378752ull
// not zeroed (fully overwritten before read):
#define OFF_WA     82378752ull              /* 9*1024*2048 bf16  37,748,736 */
#define OFF_WB     120127488ull             /* 9*512*1024  bf16   9,437,184 */
#define OFF_MX     129564672ull             /* [128][81][2048] bf16 42,467,328 */
// during the mask path the MX region is dead -> split-K f32 accumulators live there:
#define OFF_M1ACC  129564672ull             /* [6272][1024] f32  25,690,112 */
#define OFF_M2ACC  155254784ull             /* [6272][512]  f32  12,845,056 */
#define SZ_MACC    38535168ull
#define OFF_LSTMW  82378752ull              /* 9*2048*2560 bf16 94,371,840 (reuses WA/WB/MX after dead) */
#define OFF_ZPART  176750592ull             /* 8*[392][2048] f32 25,690,112 */
#define ARENA_END  202440704ull

// conv epilogue flags
#define CF_BN    1
#define CF_RELU  2
#define CF_ATOM  4
#define CF_OUTF  8
#define CF_OUTB 16
#define CF_ZOFF 32

// ---------------- implicit-GEMM 3x3 SAME conv, bf16 MFMA ----------------
// Xin: padded NHWC bf16 [nImg][81][Cin] (border rows are zero)
// Wt : [9][Cout?][ldb] bf16, row = output channel, k along input channel
// tile 128(M pix) x 128(N chan), BK=32, 4 waves, wave = 64x64 via 4x4 16x16x32 MFMAs.
// Staging via global_load_lds width=16 into LINEAR [128][32]-u16 buffers.
// DEPTH-2 PIPELINE (T4 counted-vmcnt): 3 LDS buffer pairs; per K-iter:
//   s_waitcnt vmcnt(4)   -- only iter j-2's 4 loads must have landed; the
//                           newer 4 stay in flight ACROSS the barrier (never 0)
//   s_barrier            -- raw; no compiler vmcnt(0) drain
//   STAGE(j+2)           -- 4 global_load_lds into buffer (j+2)%3
//   COMPUTE(j)           -- 8 ds_read_b128 + 16 MFMA from buffer j%3
// Load-to-use distance = 2 full iters (~2000cyc) > worst HBM latency.
// Hazards: WAR on buf (j+2)%3: last read at compute j-1, all waves passed
// barrier j after finishing it -> safe. RAW: every wave's own vmcnt(4)
// precedes barrier j -> all rows of buf j%3 visible after barrier. Compiler
// ordering pinned by volatile "memory"-clobber waitcnt adjacent to barrier.
// nIter = kChunk/32 is a multiple of 3 for every call site (144/72/36/18).
// XCD remap (T1): each XCD owns a contiguous (y,z)-panel chunk.
__global__ __launch_bounds__(256)
void k_conv(const u16* __restrict__ Xin, const u16* __restrict__ Wt,
            float* __restrict__ outF, u16* __restrict__ outB,
            float* __restrict__ atomF,
            const float* __restrict__ gamma, const float* __restrict__ beta,
            int M, int Cin, int log2Cin, int ldb, int Cout, int kChunk, int flags)
{
  __shared__ u16 As[3*4096];
  __shared__ u16 Bs[3*4096];
  const int tid = threadIdx.x;

  // ---- XCD-aware tile remap ----
  int bx = blockIdx.x, by = blockIdx.y, bz = blockIdx.z;
  {
    const int gx = gridDim.x, gy = gridDim.y;
    const int P = gy * gridDim.z;          // panels = (y,z) pairs sharing a B-panel
    if ((P & 7) == 0) {
      int flat = bx + gx * (by + gy * bz);
      int xcd = flat & 7, local = flat >> 3, ppx = P >> 3;
      int x = local / ppx, pl = local - x * ppx;
      int panel = xcd * ppx + pl;
      bx = x; by = panel % gy; bz = panel / gy;
    }
  }
  const int m0 = bx*128, n0 = by*128;
  const int row0 = tid >> 2;
  // inverse swizzle on the global source chunk (read-side XOR kept)
  const int c8 = (((tid & 3) ^ (row0 & 3) ^ ((row0 >> 2) & 3))) * 8;

  long long Abase[2], Bbase[2];
  #pragma unroll
  for (int r = 0; r < 2; ++r) {
    int m = m0 + row0 + r*64; if (m > M-1) m = M-1;   // clamp: safe addr, result discarded
    int img = m / 49, p = m % 49, y = p / 7, xx = p % 7;
    Abase[r] = (long long)(img*81 + y*9 + xx) * Cin + c8;
    Bbase[r] = (long long)(n0 + row0 + r*64) * ldb + c8;
  }
  const long long tapStride = (long long)Cout * ldb;
  const int lane = tid & 63, wave = tid >> 6;
  const int l16 = lane & 15, quad = lane >> 4;
  const int wm = wave & 1, wn = wave >> 1;
  const int fsl = (quad ^ (l16 & 3) ^ ((l16 >> 2) & 3)) * 8;
  const int stg = wave*512;                 // wave-uniform staging base (u16)

  f32x4 acc[4][4];
  #pragma unroll
  for (int i=0;i<4;i++)
    #pragma unroll
    for (int j=0;j<4;j++)
      #pragma unroll
      for (int r=0;r<4;r++) acc[i][j][r] = 0.f;

  const int kStart = bz * kChunk;
  const int nIter = kChunk >> 5;            // multiple of 3, >= 18

#define VW4 asm volatile("s_waitcnt vmcnt(4)" ::: "memory")
#define VW0 asm volatile("s_waitcnt vmcnt(0)" ::: "memory")
#define BARX __builtin_amdgcn_s_barrier()

#define STAGE(IT, AB, BB) do {                                            \
    int kk_ = kStart + (IT)*32;                                           \
    int tap_ = kk_ >> log2Cin;                                            \
    int kc_  = kk_ & (Cin - 1);                                           \
    int ty_  = tap_ / 3;                                                  \
    long long off_ = ((long long)(ty_*6 + tap_) << log2Cin) + kc_;        \
    glds16(Xin + Abase[0] + off_, (AB) + stg);                            \
    glds16(Xin + Abase[1] + off_, (AB) + 2048 + stg);                     \
    const u16* wp_ = Wt + (long long)tap_ * tapStride + kc_;              \
    glds16(wp_ + Bbase[0], (BB) + stg);                                   \
    glds16(wp_ + Bbase[1], (BB) + 2048 + stg);                            \
  } while(0)

#define COMPUTE(AB, BB) do {                                              \
    const u16* Af_ = (AB) + (wm*64 + l16)*32 + fsl;                       \
    const u16* Bf_ = (BB) + (wn*64 + l16)*32 + fsl;                       \
    bf16x8 av[4], bv[4];                                                  \
    _Pragma("unroll")                                                     \
    for (int i=0;i<4;i++) av[i] = *(const bf16x8*)(Af_ + i*512);          \
    _Pragma("unroll")                                                     \
    for (int j=0;j<4;j++) bv[j] = *(const bf16x8*)(Bf_ + j*512);          \
    _Pragma("unroll")                                                     \
    for (int i=0;i<4;i++)                                                 \
      _Pragma("unroll")                                                   \
      for (int j=0;j<4;j++)                                               \
        acc[i][j] = __builtin_amdgcn_mfma_f32_16x16x32_bf16(av[i], bv[j], acc[i][j], 0, 0, 0); \
  } while(0)

  // prologue: stage iters 0,1 into buffers 0,1
  STAGE(0, As + 0,    Bs + 0);
  STAGE(1, As + 4096, Bs + 4096);
  // main loop, x3 unrolled (nIter % 3 == 0); buffer of iter j = j%3
  for (int it = 0; it < nIter; it += 3) {
    // slot 0: j = it   -> compute buf0, stage buf2 (iter it+2)
    VW4; BARX;
    if (it + 2 < nIter) STAGE(it + 2, As + 8192, Bs + 8192);
    COMPUTE(As + 0, Bs + 0);
    // slot 1: j = it+1 -> compute buf1, stage buf0 (iter it+3)
    VW4; BARX;
    if (it + 3 < nIter) STAGE(it + 3, As + 0, Bs + 0);
    COMPUTE(As + 4096, Bs + 4096);
    // slot 2: j = it+2 -> compute buf2, stage buf1 (iter it+4)
    if (it + 3 < nIter) { VW4; } else { VW0; }
    BARX;
    if (it + 4 < nIter) STAGE(it + 4, As + 4096, Bs + 4096);
    COMPUTE(As + 8192, Bs + 8192);
  }
#undef STAGE
#undef COMPUTE
#undef VW4
#undef VW0
#undef BARX

  float* outFz = outF;
  if (flags & CF_ZOFF) outFz = outF + (long long)bz * M * Cout;
  #pragma unroll
  for (int i=0;i<4;i++) {
    #pragma unroll
    for (int r=0;r<4;r++) {
      int m = m0 + wm*64 + i*16 + quad*4 + r;
      if (m >= M) continue;
      int img = m / 49, p = m % 49;
      int pp = (p/7 + 1)*9 + (p%7) + 1;
      #pragma unroll
      for (int j=0;j<4;j++) {
        int n = n0 + wn*64 + j*16 + l16;
        float v = acc[i][j][r];
        if (flags & CF_BN)   v = v * (gamma[n]*BNRS) + beta[n];
        if (flags & CF_RELU) v = fmaxf(v, 0.f);
        if (flags & CF_ATOM) atomicAdd(atomF + (long long)m*Cout + n, v);
        if (flags & CF_OUTF) outFz[(long long)m*Cout + n] = v;
        if (flags & CF_OUTB) outB[((long long)img*81 + pp)*Cout + n] = f2bf(v);
      }
    }
  }
}

// W[O][I][3][3] f32 -> Wt[tap][o][i] bf16   (reads 36B/thread contiguous, writes coalesced)
__global__ void k_wtrans(const float* __restrict__ W, u16* __restrict__ Wt, int total) {
  int idx = blockIdx.x*256 + threadIdx.x;
  if (idx >= total) return;
  const float* src = W + (long long)idx*9;
  #pragma unroll
  for (int tap=0; tap<9; ++tap)
    Wt[(long long)tap*total + idx] = f2bf(src[tap]);
}

// input_x (8,2048,16,7,7) f32 -> Xn [128][81][2048] bf16 (interior only)
__global__ void k_transpose(const float* __restrict__ x, u16* __restrict__ Xn) {
  int idx = blockIdx.x*256 + threadIdx.x;   // 8*256*49 = 100352
  int p = idx % 49; int r = idx / 49; int c8 = (r & 255)*8; int b = r >> 8;
  if (b >= 8) return;
  int pp = (p/7 + 1)*9 + (p%7) + 1;
  for (int t=0; t<16; ++t) {
    u16 o[8];
    #pragma unroll
    for (int j=0;j<8;j++)
      o[j] = f2bf(x[((long long)(b*2048 + c8 + j)*16 + t)*49 + p]);
    *(uint4*)&Xn[((long long)(b*16+t)*81 + pp)*2048 + c8] = *(uint4*)o;
  }
}

// mask conv3 (512->1) + sigmoid, one block per output pixel
__global__ void k_mask3(const u16* __restrict__ M2b, const float* __restrict__ w3,
                        float* __restrict__ maskOut) {
  int img = blockIdx.x / 49, p = blockIdx.x % 49;
  int y = p/7, xx = p%7;
  int lane = threadIdx.x;
  float s = 0.f;
  for (int k = lane; k < 4608; k += 64) {
    int tap = k >> 9, c = k & 511;
    int ty = tap/3, tx = tap - ty*3;
    int pp = (y+ty)*9 + xx + tx;
    s += bf2f(M2b[((long long)img*81 + pp)*512 + c]) * w3[c*9 + tap];
  }
  #pragma unroll
  for (int off=32; off>0; off>>=1) s += __shfl_down(s, off, 64);
  if (lane == 0) maskOut[blockIdx.x] = 1.f/(1.f + expf(-s));
}

__global__ void k_losses(const float* __restrict__ mk, float* __restrict__ dout) {
  __shared__ float s1[256], s2[256];
  int tid = threadIdx.x;
  float tv = 0.f, ct = 0.f;
  for (int i = tid; i < 128*7*6; i += 256) {          // horizontal diffs
    int img = i / 42, r = i % 42, y = r / 6, xx = r % 6;
    int base = img*49 + y*7 + xx;
    tv += fabsf(mk[base+1] - mk[base]);
  }
  for (int i = tid; i < 128*6*7; i += 256) {          // vertical diffs
    int img = i / 42, r = i % 42, y = r / 7, xx = r % 7;
    int base = img*49 + y*7 + xx;
    tv += fabsf(mk[base+7] - mk[base]);
  }
  for (int i = tid; i < 6272; i += 256) {
    float v = mk[i];
    ct += (v < 0.5f ? v : 0.f) - (v > 0.5f ? v : 0.f);
  }
  s1[tid] = tv; s2[tid] = ct; __syncthreads();
  for (int off=128; off>0; off>>=1) {
    if (tid < off) { s1[tid]+=s1[tid+off]; s2[tid]+=s2[tid+off]; }
    __syncthreads();
  }
  if (tid==0) { dout[6424] = 1e-5f * s1[0]; dout[6425] = (1e-4f*0.5f/8.f) * s2[0]; }
}

// mx = mask*x (bf16, padded NHWC) and mean over T
__global__ void k_mx(const float* __restrict__ x, const float* __restrict__ mk,
                     u16* __restrict__ mxn, u16* __restrict__ meanx) {
  int idx = blockIdx.x*256 + threadIdx.x;
  int p = idx % 49; int r = idx / 49; int c8 = (r & 255)*8; int b = r >> 8;
  if (b >= 8) return;
  int pp = (p/7+1)*9 + (p%7) + 1;
  float macc[8] = {0,0,0,0,0,0,0,0};
  for (int t=0;t<16;++t) {
    float mval = mk[(b*16+t)*49 + p];
    u16 o[8];
    #pragma unroll
    for (int j=0;j<8;j++) {
      float v = x[((long long)(b*2048 + c8 + j)*16 + t)*49 + p] * mval;
      o[j] = f2bf(v); macc[j] += v;
    }
    *(uint4*)&mxn[((long long)(b*16+t)*81 + pp)*2048 + c8] = *(uint4*)o;
  }
  u16 o2[8];
  #pragma unroll
  for (int j=0;j<8;j++) o2[j] = f2bf(macc[j] * (1.f/16.f));
  *(uint4*)&meanx[((long long)b*81 + pp)*2048 + c8] = *(uint4*)o2;
}

// att_fea[img] = (1/49) * sum_{p,c} mx * att_fw[c]
__global__ void k_att(const u16* __restrict__ mxn, const float* __restrict__ fw,
                      float* __restrict__ fea) {
  __shared__ float red[256];
  int img = blockIdx.x, tid = threadIdx.x;
  const u16* base = mxn + (long long)img*81*2048;
  float s = 0.f;
  for (int k = tid; k < 49*2048; k += 256) {
    int p = k >> 11, c = k & 2047;
    int pp = (p/7+1)*9 + (p%7) + 1;
    s += bf2f(base[(long long)pp*2048 + c]) * fw[c];
  }
  red[tid] = s; __syncthreads();
  for (int off=128; off>0; off>>=1) { if (tid<off) red[tid]+=red[tid+off]; __syncthreads(); }
  if (tid==0) fea[img] = red[0] * (1.f/49.f);
}

// softmax over T (att_h is (B,1): shift-invariant, w identical every step)
__global__ void k_softmax(const float* __restrict__ fea, float* __restrict__ w,
                          float* __restrict__ doutW) {
  int b = threadIdx.x;
  if (b >= 8) return;
  float mx = -1e30f;
  for (int t=0;t<16;t++) mx = fmaxf(mx, fea[b*16+t]);
  float e[16], s = 0.f;
  for (int t=0;t<16;t++) { e[t] = expf(fea[b*16+t]-mx); s += e[t]; }
  float inv = 1.f/s;
  for (int t=0;t<16;t++) { float v = e[t]*inv; w[b*16+t] = v; doutW[b*16+t] = v; }
}

// xt = sum_t w[b,t]*mx[b,t]  (bf16, padded NHWC)
__global__ void k_xt(const u16* __restrict__ mxn, const float* __restrict__ w,
                     u16* __restrict__ xtn) {
  int idx = blockIdx.x*256 + threadIdx.x;
  int c8 = (idx & 255)*8; int r = idx >> 8; int p = r % 49; int b = r / 49;
  if (b >= 8) return;
  int pp = (p/7+1)*9 + (p%7)+1;
  float a[8] = {0,0,0,0,0,0,0,0};
  for (int t=0;t<16;t++) {
    float wt = w[b*16+t];
    uint4 raw = *(const uint4*)&mxn[((long long)(b*16+t)*81 + pp)*2048 + c8];
    const u16* h = (const u16*)&raw;
    #pragma unroll
    for (int j=0;j<8;j++) a[j] += wt * bf2f(h[j]);
  }
  u16 o[8];
  #pragma unroll
  for (int j=0;j<8;j++) o[j] = f2bf(a[j]);
  *(uint4*)&xtn[((long long)b*81+pp)*2048 + c8] = *(uint4*)o;
}

// split-K atomic accum -> BN+ReLU -> bf16 padded (borders zeroed) and/or f32 compact
__global__ void k_finalize(const float* __restrict__ acc, const float* __restrict__ bn,
                           u16* __restrict__ outB, float* __restrict__ outF,
                           int C, int nImg) {
  int idx = blockIdx.x*256 + threadIdx.x;
  int total = nImg*81*C;
  if (idx >= total) return;
  int c = idx % C; int r = idx / C; int pp = r % 81; int img = r / 81;
  int py = pp/9, px = pp%9;
  bool inter = (py>=1 && py<=7 && px>=1 && px<=7);
  float v = 0.f;
  int m = img*49 + (py-1)*7 + (px-1);
  if (inter) {
    v = acc[(long long)m*C + c];
    v = v*(bn[c]*BNRS) + bn[C+c];
    v = fmaxf(v, 0.f);
  }
  if (outB) outB[idx] = f2bf(v);
  if (outF && inter) outF[(long long)m*C + c] = v;
}

// LSTM gates: z = zx + lstm_b + sum_s zpart[s]; update c,h; accumulate outs mean
__global__ void k_gate(const float* __restrict__ zx, const float* __restrict__ zp,
                       const float* __restrict__ lb, float* __restrict__ cst,
                       u16* __restrict__ hn, float* __restrict__ outs) {
  int idx = blockIdx.x*256 + threadIdx.x;
  if (idx >= 392*512) return;
  int c = idx & 511; int m = idx >> 9;
  int b = m / 49, p = m % 49;
  int pp = (p/7+1)*9 + (p%7)+1;
  const float* zr = zx + (long long)m*2048;
  float zi = zr[c]        + lb[c];
  float zf = zr[c+512]    + lb[c+512];
  float zo = zr[c+1024]   + lb[c+1024];
  float zg = zr[c+1536]   + lb[c+1536];
  #pragma unroll
  for (int s=0;s<8;s++) {
    const float* q = zp + ((long long)s*392 + m)*2048;
    zi += q[c]; zf += q[c+512]; zo += q[c+1024]; zg += q[c+1536];
  }
  float si = 1.f/(1.f+expf(-zi));
  float sf = 1.f/(1.f+expf(-zf));
  float so = 1.f/(1.f+expf(-zo));
  float cn = sf*cst[idx] + si*tanhf(zg);
  float h  = so*tanhf(cn);
  cst[idx] = cn;
  hn[((long long)b*81 + pp)*512 + c] = f2bf(h);
  atomicAdd(outs + b*512 + c, h*(1.f/784.f));   // /49 pixels /16 steps
}

__global__ void k_fc(const float* __restrict__ outs, const float* __restrict__ fcw,
                     const float* __restrict__ fcb, float* __restrict__ dout) {
  int t = threadIdx.x;
  if (t >= 24) return;
  int b = t / 3, j = t % 3;
  float s = fcb[j];
  for (int c=0;c<512;c++) s += outs[b*512+c]*fcw[j*512+c];
  dout[b*3+j] = s;
}

extern "C" void kernel_launch(void* const* d_in, const int* in_sizes, int n_in,
                              void* d_out, int out_size, void* d_ws, size_t ws_size,
                              hipStream_t stream) {
  (void)in_sizes; (void)n_in; (void)out_size;
  const float* x        = (const float*)d_in[0];
  const float* mask_w1  = (const float*)d_in[1];
  const float* mask_bn1 = (const float*)d_in[2];
  const float* mask_w2  = (const float*)d_in[3];
  const float* mask_bn2 = (const float*)d_in[4];
  const float* mask_w3  = (const float*)d_in[5];
  const float* h0_w1    = (const float*)d_in[6];
  const float* h0_bn1   = (const float*)d_in[7];
  const float* h0_w2    = (const float*)d_in[8];
  const float* h0_bn2   = (const float*)d_in[9];
  const float* c0_w1    = (const float*)d_in[10];
  const float* c0_bn1   = (const float*)d_in[11];
  const float* c0_w2    = (const float*)d_in[12];
  const float* c0_bn2   = (const float*)d_in[13];
  const float* att_fw   = (const float*)d_in[14];
  // d_in[15] = att_hw: mathematically irrelevant (softmax shift-invariance)
  const float* lstm_w   = (const float*)d_in[16];
  const float* lstm_b   = (const float*)d_in[17];
  const float* fc_w     = (const float*)d_in[18];
  const float* fc_b     = (const float*)d_in[19];
  float* dout = (float*)d_out;
  char* ws = (char*)d_ws;
  if (ws_size < ARENA_END) return;

  u16* XN    = (u16*)(ws + OFF_XN);
  u16* M1b   = (u16*)(ws + OFF_M1);
  u16* M2b   = (u16*)(ws + OFF_M2);
  u16* MEANX = (u16*)(ws + OFF_MEANX);
  u16* XTN   = (u16*)(ws + OFF_XTN);
  u16* TH1   = (u16*)(ws + OFF_TH1);
  u16* TC1   = (u16*)(ws + OFF_TC1);
  u16* HN    = (u16*)(ws + OFF_HN);
  float* CST   = (float*)(ws + OFF_CST);
  float* ZXACC = (float*)(ws + OFF_ZXACC);
  float* ATH1  = (float*)(ws + OFF_ATH1);
  float* ATC1  = (float*)(ws + OFF_ATC1);
  float* ATH2  = (float*)(ws + OFF_ATH2);
  float* ATC2  = (float*)(ws + OFF_ATC2);
  float* FEA   = (float*)(ws + OFF_FEA);
  float* Wbuf  = (float*)(ws + OFF_W);
  float* OUTS  = (float*)(ws + OFF_OUTS);
  u16* WA    = (u16*)(ws + OFF_WA);
  u16* WB    = (u16*)(ws + OFF_WB);
  u16* MX    = (u16*)(ws + OFF_MX);
  u16* LSTMW = (u16*)(ws + OFF_LSTMW);
  float* ZPART = (float*)(ws + OFF_ZPART);
  float* M1ACC = (float*)(ws + OFF_M1ACC);
  float* M2ACC = (float*)(ws + OFF_M2ACC);

  hipMemsetAsync(ws, 0, (size_t)Z0_END, stream);
  hipMemsetAsync(ws + OFF_M1ACC, 0, (size_t)SZ_MACC, stream);  // split-K accumulators

  // ---- mask path (split-K z=4) ----
  k_wtrans<<<8192, 256, 0, stream>>>(mask_w1, WA, 1024*2048);
  k_wtrans<<<2048, 256, 0, stream>>>(mask_w2, WB, 512*1024);
  k_transpose<<<392, 256, 0, stream>>>(x, XN);
  k_conv<<<dim3(49,8,4),256,0,stream>>>(XN, WA, nullptr, nullptr, M1ACC,
      nullptr, nullptr, 6272, 2048, 11, 2048, 1024, 4608, CF_ATOM);
  k_finalize<<<41472, 256, 0, stream>>>(M1ACC, mask_bn1, M1b, nullptr, 1024, 128);
  k_conv<<<dim3(49,4,4),256,0,stream>>>(M1b, WB, nullptr, nullptr, M2ACC,
      nullptr, nullptr, 6272, 1024, 10, 1024, 512, 2304, CF_ATOM);
  k_finalize<<<20736, 256, 0, stream>>>(M2ACC, mask_bn2, M2b, nullptr, 512, 128);
  k_mask3<<<6272, 64, 0, stream>>>(M2b, mask_w3, dout+152);
  k_losses<<<1, 256, 0, stream>>>(dout+152, dout);

  // ---- attention-weighted features ----
  hipMemsetAsync(ws + OFF_M2, 0, (size_t)SZ_M2, stream);   // re-zero reused region (borders)
  k_mx<<<392, 256, 0, stream>>>(x, dout+152, MX, MEANX);
  k_att<<<128, 256, 0, stream>>>(MX, att_fw, FEA);
  k_softmax<<<1, 64, 0, stream>>>(FEA, Wbuf, dout+24);
  k_xt<<<392, 256, 0, stream>>>(MX, Wbuf, XTN);

  // ---- h0 path (z=16) ----
  k_wtrans<<<8192, 256, 0, stream>>>(h0_w1, WA, 1024*2048);
  k_wtrans<<<2048, 256, 0, stream>>>(h0_w2, WB, 512*1024);
  k_conv<<<dim3(4,8,16),256,0,stream>>>(MEANX, WA, nullptr, nullptr, ATH1,
      nullptr, nullptr, 392, 2048, 11, 2048, 1024, 1152, CF_ATOM);
  k_finalize<<<2592, 256, 0, stream>>>(ATH1, h0_bn1, TH1, nullptr, 1024, 8);
  k_conv<<<dim3(4,4,16),256,0,stream>>>(TH1, WB, nullptr, nullptr, ATH2,
      nullptr, nullptr, 392, 1024, 10, 1024, 512, 576, CF_ATOM);
  k_finalize<<<1296, 256, 0, stream>>>(ATH2, h0_bn2, HN, nullptr, 512, 8);

  // ---- c0 path (z=16) ----
  k_wtrans<<<8192, 256, 0, stream>>>(c0_w1, WA, 1024*2048);
  k_wtrans<<<2048, 256, 0, stream>>>(c0_w2, WB, 512*1024);
  k_conv<<<dim3(4,8,16),256,0,stream>>>(MEANX, WA, nullptr, nullptr, ATC1,
      nullptr, nullptr, 392, 2048, 11, 2048, 1024, 1152, CF_ATOM);
  k_finalize<<<2592, 256, 0, stream>>>(ATC1, c0_bn1, TC1, nullptr, 1024, 8);
  k_conv<<<dim3(4,4,16),256,0,stream>>>(TC1, WB, nullptr, nullptr, ATC2,
      nullptr, nullptr, 392, 1024, 10, 1024, 512, 576, CF_ATOM);
  k_finalize<<<1296, 256, 0, stream>>>(ATC2, c0_bn2, nullptr, CST, 512, 8);

  // ---- LSTM: zx precomputed once (w constant across steps), z=16 ----
  k_wtrans<<<20480, 256, 0, stream>>>(lstm_w, LSTMW, 2048*2560);
  k_conv<<<dim3(4,16,16),256,0,stream>>>(XTN, LSTMW, nullptr, nullptr, ZXACC,
      nullptr, nullptr, 392, 2048, 11, 2560, 2048, 1152, CF_ATOM);
  for (int step = 0; step < 16; ++step) {
    k_conv<<<dim3(4,16,8),256,0,stream>>>(HN, LSTMW+2048, ZPART, nullptr, nullptr,
        nullptr, nullptr, 392, 512, 9, 2560, 2048, 576, CF_OUTF|CF_ZOFF);
    k_gate<<<784, 256, 0, stream>>>(ZXACC, ZPART, lstm_b, CST, HN, OUTS);
  }
  k_fc<<<1, 64, 0, stream>>>(OUTS, fc_w, fc_b, dout);
}

// Round 5
// 2064.964 us; speedup vs baseline: 1.0716x; 1.0716x over previous
//
#include <hip/hip_runtime.h>
#include <cstdint>

typedef unsigned short u16;
typedef __bf16 bf16x8 __attribute__((ext_vector_type(8)));
typedef float f32x4 __attribute__((ext_vector_type(4)));

#define BNRS 0.9999950000374997f   /* 1/sqrt(1+1e-5) */

__device__ __forceinline__ u16 f2bf(float f) {
  unsigned u = __float_as_uint(f);
  u += 0x7fffu + ((u >> 16) & 1u);
  return (u16)(u >> 16);
}
__device__ __forceinline__ float bf2f(u16 h) {
  return __uint_as_float(((unsigned)h) << 16);
}

// async global->LDS DMA, 16B per lane, dest = wave-uniform base + lane*16
__device__ __forceinline__ void glds16(const u16* g, u16* l) {
  __builtin_amdgcn_global_load_lds(
      (const __attribute__((address_space(1))) void*)g,
      (__attribute__((address_space(3))) void*)l, 16, 0, 0);
}

// ---------------- workspace arena layout (bytes) ----------------
// zeroed every launch:
#define OFF_XN     0ull                     /* [128][81][2048] bf16  42,467,328 */
#define OFF_M1     42467328ull              /* [128][81][1024] bf16  21,233,664 */
#define OFF_M2     63700992ull              /* [128][81][512]  bf16  10,616,832 */
#define SZ_M2      10616832ull
// M2 region reused after mask3 (re-zeroed):
#define OFF_MEANX  63700992ull              /* [8][81][2048] bf16  2,654,208 */
#define OFF_XTN    66355200ull              /* [8][81][2048] bf16  2,654,208 */
#define OFF_TH1    69009408ull              /* [8][81][1024] bf16  1,327,104 */
#define OFF_TC1    70336512ull              /* [8][81][1024] bf16  1,327,104 */
#define OFF_HN     71663616ull              /* [8][81][512]  bf16    663,552 */
#define OFF_CST    72327168ull              /* [392][512]    f32     802,816 */
#define OFF_ZXACC  74317824ull              /* [392][2048] f32     3,211,264 */
#define OFF_ATH1   77529088ull              /* [392][1024] f32     1,605,632 */
#define OFF_ATC1   79134720ull
#define OFF_ATH2   80740352ull              /* [392][512] f32        802,816 */
#define OFF_ATC2   81543168ull
#define OFF_FEA    82345984ull              /* [128] f32 */
#define OFF_W      82346496ull              /* [128] f32 */
#define OFF_OUTS   82347008ull              /* [8][512] f32 */
#define Z0_END     82378752ull
// not zeroed (fully overwritten before read):
#define OFF_WA     82378752ull              /* 9*1024*2048 bf16  37,748,736 */
#define OFF_WB     120127488ull             /* 9*512*1024  bf16   9,437,184 */
#define OFF_MX     129564672ull             /* [128][81][2048] bf16 42,467,328 */
// during the mask path the MX region is dead -> split-K f32 accumulators live there:
#define OFF_M1ACC  129564672ull             /* [6272][1024] f32  25,690,112 */
#define OFF_M2ACC  155254784ull             /* [6272][512]  f32  12,845,056 */
#define SZ_MACC    38535168ull
#define OFF_LSTMW  82378752ull              /* 9*2048*2560 bf16 94,371,840 (reuses WA/WB/MX after dead) */
#define OFF_ZPART  176750592ull             /* 8*[392][2048] f32 25,690,112 */
#define ARENA_END  202440704ull

// conv epilogue flags
#define CF_BN    1
#define CF_RELU  2
#define CF_ATOM  4
#define CF_OUTF  8
#define CF_OUTB 16
#define CF_ZOFF 32

// ---------------- implicit-GEMM 3x3 SAME conv, bf16 MFMA ----------------
// Xin: padded NHWC bf16 [nImg][81][Cin] (border rows are zero)
// Wt : [9][Cout?][ldb] bf16, row = output channel, k along input channel
// tile 128(M pix) x 128(N chan), BK=32, 4 waves, wave = 64x64 via 4x4 16x16x32 MFMAs.
// Staging via global_load_lds width=16 into LINEAR [64]x[32]-u16 half-buffers.
// DEPTH-2 PIPELINE (T4 counted-vmcnt), 3 buffer pairs; per K-iter:
//   s_waitcnt vmcnt(4)   -- only iter j-2's 4 loads must have landed; the
//                           newer 4 stay in flight ACROSS the barrier (never 0)
//   s_barrier            -- raw; no compiler vmcnt(0) drain
//   STAGE(j+2)           -- 4 global_load_lds into buffer (j+2)%3
//   COMPUTE(j)           -- 8 ds_read_b128 + 16 MFMA from buffer j%3
// R4 LESSON: the 3 buffers MUST be SEPARATE __shared__ objects. With one
// merged As[3*4096], hipcc cannot disambiguate ds_read(buf j) from in-flight
// DMA writes (buf j+2) within the same object and inserts a conservative
// s_waitcnt vmcnt(0) before the fragment reads -> pipeline depth collapses
// to 0 and every iter eats a full load latency (measured: 1072->1450
// cyc/iter). Separate named arrays give LLVM distinct base symbols.
// Hazards (verified R4, correctness passed): WAR on buf (j+2)%3 -- last read
// at compute j-1, all waves passed barrier j after finishing it. RAW -- every
// wave's vmcnt(4) precedes barrier j, so all of buf j%3 is visible after it.
// Tail: final trip uses vmcnt(0) on the last slot only.
// nIter = kChunk/32 is a multiple of 3 for every call site (144/72/36/18).
// XCD remap (T1): each XCD owns a contiguous (y,z)-panel chunk.
__global__ __launch_bounds__(256)
void k_conv(const u16* __restrict__ Xin, const u16* __restrict__ Wt,
            float* __restrict__ outF, u16* __restrict__ outB,
            float* __restrict__ atomF,
            const float* __restrict__ gamma, const float* __restrict__ beta,
            int M, int Cin, int log2Cin, int ldb, int Cout, int kChunk, int flags)
{
  __shared__ u16 As0[4096], As1[4096], As2[4096];
  __shared__ u16 Bs0[4096], Bs1[4096], Bs2[4096];
  const int tid = threadIdx.x;

  // ---- XCD-aware tile remap ----
  int bx = blockIdx.x, by = blockIdx.y, bz = blockIdx.z;
  {
    const int gx = gridDim.x, gy = gridDim.y;
    const int P = gy * gridDim.z;          // panels = (y,z) pairs sharing a B-panel
    if ((P & 7) == 0) {
      int flat = bx + gx * (by + gy * bz);
      int xcd = flat & 7, local = flat >> 3, ppx = P >> 3;
      int x = local / ppx, pl = local - x * ppx;
      int panel = xcd * ppx + pl;
      bx = x; by = panel % gy; bz = panel / gy;
    }
  }
  const int m0 = bx*128, n0 = by*128;
  const int row0 = tid >> 2;
  // inverse swizzle on the global source chunk (read-side XOR kept)
  const int c8 = (((tid & 3) ^ (row0 & 3) ^ ((row0 >> 2) & 3))) * 8;

  long long Abase[2], Bbase[2];
  #pragma unroll
  for (int r = 0; r < 2; ++r) {
    int m = m0 + row0 + r*64; if (m > M-1) m = M-1;   // clamp: safe addr, result discarded
    int img = m / 49, p = m % 49, y = p / 7, xx = p % 7;
    Abase[r] = (long long)(img*81 + y*9 + xx) * Cin + c8;
    Bbase[r] = (long long)(n0 + row0 + r*64) * ldb + c8;
  }
  const long long tapStride = (long long)Cout * ldb;
  const int lane = tid & 63, wave = tid >> 6;
  const int l16 = lane & 15, quad = lane >> 4;
  const int wm = wave & 1, wn = wave >> 1;
  const int fsl = (quad ^ (l16 & 3) ^ ((l16 >> 2) & 3)) * 8;
  const int stg = wave*512;                 // wave-uniform staging base (u16)

  f32x4 acc[4][4];
  #pragma unroll
  for (int i=0;i<4;i++)
    #pragma unroll
    for (int j=0;j<4;j++)
      #pragma unroll
      for (int r=0;r<4;r++) acc[i][j][r] = 0.f;

  const int kStart = bz * kChunk;
  const int nIter = kChunk >> 5;            // multiple of 3, >= 18

#define VW4 asm volatile("s_waitcnt vmcnt(4)" ::: "memory")
#define VW0 asm volatile("s_waitcnt vmcnt(0)" ::: "memory")
#define BARX __builtin_amdgcn_s_barrier()

#define STAGE(IT, AB, BB) do {                                            \
    int kk_ = kStart + (IT)*32;                                           \
    int tap_ = kk_ >> log2Cin;                                            \
    int kc_  = kk_ & (Cin - 1);                                           \
    int ty_  = tap_ / 3;                                                  \
    long long off_ = ((long long)(ty_*6 + tap_) << log2Cin) + kc_;        \
    glds16(Xin + Abase[0] + off_, (AB) + stg);                            \
    glds16(Xin + Abase[1] + off_, (AB) + 2048 + stg);                     \
    const u16* wp_ = Wt + (long long)tap_ * tapStride + kc_;              \
    glds16(wp_ + Bbase[0], (BB) + stg);                                   \
    glds16(wp_ + Bbase[1], (BB) + 2048 + stg);                            \
  } while(0)

#define COMPUTE(AB, BB) do {                                              \
    const u16* Af_ = (AB) + (wm*64 + l16)*32 + fsl;                       \
    const u16* Bf_ = (BB) + (wn*64 + l16)*32 + fsl;                       \
    bf16x8 av[4], bv[4];                                                  \
    _Pragma("unroll")                                                     \
    for (int i=0;i<4;i++) av[i] = *(const bf16x8*)(Af_ + i*512);          \
    _Pragma("unroll")                                                     \
    for (int j=0;j<4;j++) bv[j] = *(const bf16x8*)(Bf_ + j*512);          \
    _Pragma("unroll")                                                     \
    for (int i=0;i<4;i++)                                                 \
      _Pragma("unroll")                                                   \
      for (int j=0;j<4;j++)                                               \
        acc[i][j] = __builtin_amdgcn_mfma_f32_16x16x32_bf16(av[i], bv[j], acc[i][j], 0, 0, 0); \
  } while(0)

  // prologue: stage iters 0,1 into buffers 0,1
  STAGE(0, As0, Bs0);
  STAGE(1, As1, Bs1);
  // main loop, x3 unrolled (nIter % 3 == 0); buffer of iter j = j%3
  for (int it = 0; it < nIter; it += 3) {
    // slot 0: j = it   -> compute buf0, stage buf2 (iter it+2)
    VW4; BARX;
    if (it + 2 < nIter) STAGE(it + 2, As2, Bs2);
    COMPUTE(As0, Bs0);
    // slot 1: j = it+1 -> compute buf1, stage buf0 (iter it+3)
    VW4; BARX;
    if (it + 3 < nIter) STAGE(it + 3, As0, Bs0);
    COMPUTE(As1, Bs1);
    // slot 2: j = it+2 -> compute buf2, stage buf1 (iter it+4)
    if (it + 3 < nIter) { VW4; } else { VW0; }
    BARX;
    if (it + 4 < nIter) STAGE(it + 4, As1, Bs1);
    COMPUTE(As2, Bs2);
  }
#undef STAGE
#undef COMPUTE
#undef VW4
#undef VW0
#undef BARX

  float* outFz = outF;
  if (flags & CF_ZOFF) outFz = outF + (long long)bz * M * Cout;
  #pragma unroll
  for (int i=0;i<4;i++) {
    #pragma unroll
    for (int r=0;r<4;r++) {
      int m = m0 + wm*64 + i*16 + quad*4 + r;
      if (m >= M) continue;
      int img = m / 49, p = m % 49;
      int pp = (p/7 + 1)*9 + (p%7) + 1;
      #pragma unroll
      for (int j=0;j<4;j++) {
        int n = n0 + wn*64 + j*16 + l16;
        float v = acc[i][j][r];
        if (flags & CF_BN)   v = v * (gamma[n]*BNRS) + beta[n];
        if (flags & CF_RELU) v = fmaxf(v, 0.f);
        if (flags & CF_ATOM) atomicAdd(atomF + (long long)m*Cout + n, v);
        if (flags & CF_OUTF) outFz[(long long)m*Cout + n] = v;
        if (flags & CF_OUTB) outB[((long long)img*81 + pp)*Cout + n] = f2bf(v);
      }
    }
  }
}

// W[O][I][3][3] f32 -> Wt[tap][o][i] bf16   (reads 36B/thread contiguous, writes coalesced)
__global__ void k_wtrans(const float* __restrict__ W, u16* __restrict__ Wt, int total) {
  int idx = blockIdx.x*256 + threadIdx.x;
  if (idx >= total) return;
  const float* src = W + (long long)idx*9;
  #pragma unroll
  for (int tap=0; tap<9; ++tap)
    Wt[(long long)tap*total + idx] = f2bf(src[tap]);
}

// input_x (8,2048,16,7,7) f32 -> Xn [128][81][2048] bf16 (interior only)
__global__ void k_transpose(const float* __restrict__ x, u16* __restrict__ Xn) {
  int idx = blockIdx.x*256 + threadIdx.x;   // 8*256*49 = 100352
  int p = idx % 49; int r = idx / 49; int c8 = (r & 255)*8; int b = r >> 8;
  if (b >= 8) return;
  int pp = (p/7 + 1)*9 + (p%7) + 1;
  for (int t=0; t<16; ++t) {
    u16 o[8];
    #pragma unroll
    for (int j=0;j<8;j++)
      o[j] = f2bf(x[((long long)(b*2048 + c8 + j)*16 + t)*49 + p]);
    *(uint4*)&Xn[((long long)(b*16+t)*81 + pp)*2048 + c8] = *(uint4*)o;
  }
}

// mask conv3 (512->1) + sigmoid, one block per output pixel
__global__ void k_mask3(const u16* __restrict__ M2b, const float* __restrict__ w3,
                        float* __restrict__ maskOut) {
  int img = blockIdx.x / 49, p = blockIdx.x % 49;
  int y = p/7, xx = p%7;
  int lane = threadIdx.x;
  float s = 0.f;
  for (int k = lane; k < 4608; k += 64) {
    int tap = k >> 9, c = k & 511;
    int ty = tap/3, tx = tap - ty*3;
    int pp = (y+ty)*9 + xx + tx;
    s += bf2f(M2b[((long long)img*81 + pp)*512 + c]) * w3[c*9 + tap];
  }
  #pragma unroll
  for (int off=32; off>0; off>>=1) s += __shfl_down(s, off, 64);
  if (lane == 0) maskOut[blockIdx.x] = 1.f/(1.f + expf(-s));
}

__global__ void k_losses(const float* __restrict__ mk, float* __restrict__ dout) {
  __shared__ float s1[256], s2[256];
  int tid = threadIdx.x;
  float tv = 0.f, ct = 0.f;
  for (int i = tid; i < 128*7*6; i += 256) {          // horizontal diffs
    int img = i / 42, r = i % 42, y = r / 6, xx = r % 6;
    int base = img*49 + y*7 + xx;
    tv += fabsf(mk[base+1] - mk[base]);
  }
  for (int i = tid; i < 128*6*7; i += 256) {          // vertical diffs
    int img = i / 42, r = i % 42, y = r / 7, xx = r % 7;
    int base = img*49 + y*7 + xx;
    tv += fabsf(mk[base+7] - mk[base]);
  }
  for (int i = tid; i < 6272; i += 256) {
    float v = mk[i];
    ct += (v < 0.5f ? v : 0.f) - (v > 0.5f ? v : 0.f);
  }
  s1[tid] = tv; s2[tid] = ct; __syncthreads();
  for (int off=128; off>0; off>>=1) {
    if (tid < off) { s1[tid]+=s1[tid+off]; s2[tid]+=s2[tid+off]; }
    __syncthreads();
  }
  if (tid==0) { dout[6424] = 1e-5f * s1[0]; dout[6425] = (1e-4f*0.5f/8.f) * s2[0]; }
}

// mx = mask*x (bf16, padded NHWC) and mean over T
__global__ void k_mx(const float* __restrict__ x, const float* __restrict__ mk,
                     u16* __restrict__ mxn, u16* __restrict__ meanx) {
  int idx = blockIdx.x*256 + threadIdx.x;
  int p = idx % 49; int r = idx / 49; int c8 = (r & 255)*8; int b = r >> 8;
  if (b >= 8) return;
  int pp = (p/7+1)*9 + (p%7) + 1;
  float macc[8] = {0,0,0,0,0,0,0,0};
  for (int t=0;t<16;++t) {
    float mval = mk[(b*16+t)*49 + p];
    u16 o[8];
    #pragma unroll
    for (int j=0;j<8;j++) {
      float v = x[((long long)(b*2048 + c8 + j)*16 + t)*49 + p] * mval;
      o[j] = f2bf(v); macc[j] += v;
    }
    *(uint4*)&mxn[((long long)(b*16+t)*81 + pp)*2048 + c8] = *(uint4*)o;
  }
  u16 o2[8];
  #pragma unroll
  for (int j=0;j<8;j++) o2[j] = f2bf(macc[j] * (1.f/16.f));
  *(uint4*)&meanx[((long long)b*81 + pp)*2048 + c8] = *(uint4*)o2;
}

// att_fea[img] = (1/49) * sum_{p,c} mx * att_fw[c]
__global__ void k_att(const u16* __restrict__ mxn, const float* __restrict__ fw,
                      float* __restrict__ fea) {
  __shared__ float red[256];
  int img = blockIdx.x, tid = threadIdx.x;
  const u16* base = mxn + (long long)img*81*2048;
  float s = 0.f;
  for (int k = tid; k < 49*2048; k += 256) {
    int p = k >> 11, c = k & 2047;
    int pp = (p/7+1)*9 + (p%7) + 1;
    s += bf2f(base[(long long)pp*2048 + c]) * fw[c];
  }
  red[tid] = s; __syncthreads();
  for (int off=128; off>0; off>>=1) { if (tid<off) red[tid]+=red[tid+off]; __syncthreads(); }
  if (tid==0) fea[img] = red[0] * (1.f/49.f);
}

// softmax over T (att_h is (B,1): shift-invariant, w identical every step)
__global__ void k_softmax(const float* __restrict__ fea, float* __restrict__ w,
                          float* __restrict__ doutW) {
  int b = threadIdx.x;
  if (b >= 8) return;
  float mx = -1e30f;
  for (int t=0;t<16;t++) mx = fmaxf(mx, fea[b*16+t]);
  float e[16], s = 0.f;
  for (int t=0;t<16;t++) { e[t] = expf(fea[b*16+t]-mx); s += e[t]; }
  float inv = 1.f/s;
  for (int t=0;t<16;t++) { float v = e[t]*inv; w[b*16+t] = v; doutW[b*16+t] = v; }
}

// xt = sum_t w[b,t]*mx[b,t]  (bf16, padded NHWC)
__global__ void k_xt(const u16* __restrict__ mxn, const float* __restrict__ w,
                     u16* __restrict__ xtn) {
  int idx = blockIdx.x*256 + threadIdx.x;
  int c8 = (idx & 255)*8; int r = idx >> 8; int p = r % 49; int b = r / 49;
  if (b >= 8) return;
  int pp = (p/7+1)*9 + (p%7)+1;
  float a[8] = {0,0,0,0,0,0,0,0};
  for (int t=0;t<16;t++) {
    float wt = w[b*16+t];
    uint4 raw = *(const uint4*)&mxn[((long long)(b*16+t)*81 + pp)*2048 + c8];
    const u16* h = (const u16*)&raw;
    #pragma unroll
    for (int j=0;j<8;j++) a[j] += wt * bf2f(h[j]);
  }
  u16 o[8];
  #pragma unroll
  for (int j=0;j<8;j++) o[j] = f2bf(a[j]);
  *(uint4*)&xtn[((long long)b*81+pp)*2048 + c8] = *(uint4*)o;
}

// split-K atomic accum -> BN+ReLU -> bf16 padded (borders zeroed) and/or f32 compact
__global__ void k_finalize(const float* __restrict__ acc, const float* __restrict__ bn,
                           u16* __restrict__ outB, float* __restrict__ outF,
                           int C, int nImg) {
  int idx = blockIdx.x*256 + threadIdx.x;
  int total = nImg*81*C;
  if (idx >= total) return;
  int c = idx % C; int r = idx / C; int pp = r % 81; int img = r / 81;
  int py = pp/9, px = pp%9;
  bool inter = (py>=1 && py<=7 && px>=1 && px<=7);
  float v = 0.f;
  int m = img*49 + (py-1)*7 + (px-1);
  if (inter) {
    v = acc[(long long)m*C + c];
    v = v*(bn[c]*BNRS) + bn[C+c];
    v = fmaxf(v, 0.f);
  }
  if (outB) outB[idx] = f2bf(v);
  if (outF && inter) outF[(long long)m*C + c] = v;
}

// LSTM gates: z = zx + lstm_b + sum_s zpart[s]; update c,h; accumulate outs mean
__global__ void k_gate(const float* __restrict__ zx, const float* __restrict__ zp,
                       const float* __restrict__ lb, float* __restrict__ cst,
                       u16* __restrict__ hn, float* __restrict__ outs) {
  int idx = blockIdx.x*256 + threadIdx.x;
  if (idx >= 392*512) return;
  int c = idx & 511; int m = idx >> 9;
  int b = m / 49, p = m % 49;
  int pp = (p/7+1)*9 + (p%7)+1;
  const float* zr = zx + (long long)m*2048;
  float zi = zr[c]        + lb[c];
  float zf = zr[c+512]    + lb[c+512];
  float zo = zr[c+1024]   + lb[c+1024];
  float zg = zr[c+1536]   + lb[c+1536];
  #pragma unroll
  for (int s=0;s<8;s++) {
    const float* q = zp + ((long long)s*392 + m)*2048;
    zi += q[c]; zf += q[c+512]; zo += q[c+1024]; zg += q[c+1536];
  }
  float si = 1.f/(1.f+expf(-zi));
  float sf = 1.f/(1.f+expf(-zf));
  float so = 1.f/(1.f+expf(-zo));
  float cn = sf*cst[idx] + si*tanhf(zg);
  float h  = so*tanhf(cn);
  cst[idx] = cn;
  hn[((long long)b*81 + pp)*512 + c] = f2bf(h);
  atomicAdd(outs + b*512 + c, h*(1.f/784.f));   // /49 pixels /16 steps
}

__global__ void k_fc(const float* __restrict__ outs, const float* __restrict__ fcw,
                     const float* __restrict__ fcb, float* __restrict__ dout) {
  int t = threadIdx.x;
  if (t >= 24) return;
  int b = t / 3, j = t % 3;
  float s = fcb[j];
  for (int c=0;c<512;c++) s += outs[b*512+c]*fcw[j*512+c];
  dout[b*3+j] = s;
}

extern "C" void kernel_launch(void* const* d_in, const int* in_sizes, int n_in,
                              void* d_out, int out_size, void* d_ws, size_t ws_size,
                              hipStream_t stream) {
  (void)in_sizes; (void)n_in; (void)out_size;
  const float* x        = (const float*)d_in[0];
  const float* mask_w1  = (const float*)d_in[1];
  const float* mask_bn1 = (const float*)d_in[2];
  const float* mask_w2  = (const float*)d_in[3];
  const float* mask_bn2 = (const float*)d_in[4];
  const float* mask_w3  = (const float*)d_in[5];
  const float* h0_w1    = (const float*)d_in[6];
  const float* h0_bn1   = (const float*)d_in[7];
  const float* h0_w2    = (const float*)d_in[8];
  const float* h0_bn2   = (const float*)d_in[9];
  const float* c0_w1    = (const float*)d_in[10];
  const float* c0_bn1   = (const float*)d_in[11];
  const float* c0_w2    = (const float*)d_in[12];
  const float* c0_bn2   = (const float*)d_in[13];
  const float* att_fw   = (const float*)d_in[14];
  // d_in[15] = att_hw: mathematically irrelevant (softmax shift-invariance)
  const float* lstm_w   = (const float*)d_in[16];
  const float* lstm_b   = (const float*)d_in[17];
  const float* fc_w     = (const float*)d_in[18];
  const float* fc_b     = (const float*)d_in[19];
  float* dout = (float*)d_out;
  char* ws = (char*)d_ws;
  if (ws_size < ARENA_END) return;

  u16* XN    = (u16*)(ws + OFF_XN);
  u16* M1b   = (u16*)(ws + OFF_M1);
  u16* M2b   = (u16*)(ws + OFF_M2);
  u16* MEANX = (u16*)(ws + OFF_MEANX);
  u16* XTN   = (u16*)(ws + OFF_XTN);
  u16* TH1   = (u16*)(ws + OFF_TH1);
  u16* TC1   = (u16*)(ws + OFF_TC1);
  u16* HN    = (u16*)(ws + OFF_HN);
  float* CST   = (float*)(ws + OFF_CST);
  float* ZXACC = (float*)(ws + OFF_ZXACC);
  float* ATH1  = (float*)(ws + OFF_ATH1);
  float* ATC1  = (float*)(ws + OFF_ATC1);
  float* ATH2  = (float*)(ws + OFF_ATH2);
  float* ATC2  = (float*)(ws + OFF_ATC2);
  float* FEA   = (float*)(ws + OFF_FEA);
  float* Wbuf  = (float*)(ws + OFF_W);
  float* OUTS  = (float*)(ws + OFF_OUTS);
  u16* WA    = (u16*)(ws + OFF_WA);
  u16* WB    = (u16*)(ws + OFF_WB);
  u16* MX    = (u16*)(ws + OFF_MX);
  u16* LSTMW = (u16*)(ws + OFF_LSTMW);
  float* ZPART = (float*)(ws + OFF_ZPART);
  float* M1ACC = (float*)(ws + OFF_M1ACC);
  float* M2ACC = (float*)(ws + OFF_M2ACC);

  hipMemsetAsync(ws, 0, (size_t)Z0_END, stream);
  hipMemsetAsync(ws + OFF_M1ACC, 0, (size_t)SZ_MACC, stream);  // split-K accumulators

  // ---- mask path (split-K z=4) ----
  k_wtrans<<<8192, 256, 0, stream>>>(mask_w1, WA, 1024*2048);
  k_wtrans<<<2048, 256, 0, stream>>>(mask_w2, WB, 512*1024);
  k_transpose<<<392, 256, 0, stream>>>(x, XN);
  k_conv<<<dim3(49,8,4),256,0,stream>>>(XN, WA, nullptr, nullptr, M1ACC,
      nullptr, nullptr, 6272, 2048, 11, 2048, 1024, 4608, CF_ATOM);
  k_finalize<<<41472, 256, 0, stream>>>(M1ACC, mask_bn1, M1b, nullptr, 1024, 128);
  k_conv<<<dim3(49,4,4),256,0,stream>>>(M1b, WB, nullptr, nullptr, M2ACC,
      nullptr, nullptr, 6272, 1024, 10, 1024, 512, 2304, CF_ATOM);
  k_finalize<<<20736, 256, 0, stream>>>(M2ACC, mask_bn2, M2b, nullptr, 512, 128);
  k_mask3<<<6272, 64, 0, stream>>>(M2b, mask_w3, dout+152);
  k_losses<<<1, 256, 0, stream>>>(dout+152, dout);

  // ---- attention-weighted features ----
  hipMemsetAsync(ws + OFF_M2, 0, (size_t)SZ_M2, stream);   // re-zero reused region (borders)
  k_mx<<<392, 256, 0, stream>>>(x, dout+152, MX, MEANX);
  k_att<<<128, 256, 0, stream>>>(MX, att_fw, FEA);
  k_softmax<<<1, 64, 0, stream>>>(FEA, Wbuf, dout+24);
  k_xt<<<392, 256, 0, stream>>>(MX, Wbuf, XTN);

  // ---- h0 path (z=16) ----
  k_wtrans<<<8192, 256, 0, stream>>>(h0_w1, WA, 1024*2048);
  k_wtrans<<<2048, 256, 0, stream>>>(h0_w2, WB, 512*1024);
  k_conv<<<dim3(4,8,16),256,0,stream>>>(MEANX, WA, nullptr, nullptr, ATH1,
      nullptr, nullptr, 392, 2048, 11, 2048, 1024, 1152, CF_ATOM);
  k_finalize<<<2592, 256, 0, stream>>>(ATH1, h0_bn1, TH1, nullptr, 1024, 8);
  k_conv<<<dim3(4,4,16),256,0,stream>>>(TH1, WB, nullptr, nullptr, ATH2,
      nullptr, nullptr, 392, 1024, 10, 1024, 512, 576, CF_ATOM);
  k_finalize<<<1296, 256, 0, stream>>>(ATH2, h0_bn2, HN, nullptr, 512, 8);

  // ---- c0 path (z=16) ----
  k_wtrans<<<8192, 256, 0, stream>>>(c0_w1, WA, 1024*2048);
  k_wtrans<<<2048, 256, 0, stream>>>(c0_w2, WB, 512*1024);
  k_conv<<<dim3(4,8,16),256,0,stream>>>(MEANX, WA, nullptr, nullptr, ATC1,
      nullptr, nullptr, 392, 2048, 11, 2048, 1024, 1152, CF_ATOM);
  k_finalize<<<2592, 256, 0, stream>>>(ATC1, c0_bn1, TC1, nullptr, 1024, 8);
  k_conv<<<dim3(4,4,16),256,0,stream>>>(TC1, WB, nullptr, nullptr, ATC2,
      nullptr, nullptr, 392, 1024, 10, 1024, 512, 576, CF_ATOM);
  k_finalize<<<1296, 256, 0, stream>>>(ATC2, c0_bn2, nullptr, CST, 512, 8);

  // ---- LSTM: zx precomputed once (w constant across steps), z=16 ----
  k_wtrans<<<20480, 256, 0, stream>>>(lstm_w, LSTMW, 2048*2560);
  k_conv<<<dim3(4,16,16),256,0,stream>>>(XTN, LSTMW, nullptr, nullptr, ZXACC,
      nullptr, nullptr, 392, 2048, 11, 2560, 2048, 1152, CF_ATOM);
  for (int step = 0; step < 16; ++step) {
    k_conv<<<dim3(4,16,8),256,0,stream>>>(HN, LSTMW+2048, ZPART, nullptr, nullptr,
        nullptr, nullptr, 392, 512, 9, 2560, 2048, 576, CF_OUTF|CF_ZOFF);
    k_gate<<<784, 256, 0, stream>>>(ZXACC, ZPART, lstm_b, CST, HN, OUTS);
  }
  k_fc<<<1, 64, 0, stream>>>(OUTS, fc_w, fc_b, dout);
}

// Round 6
// 2008.581 us; speedup vs baseline: 1.1017x; 1.0281x over previous
//
#include <hip/hip_runtime.h>
#include <cstdint>

typedef unsigned short u16;
typedef __bf16 bf16x8 __attribute__((ext_vector_type(8)));
typedef float f32x4 __attribute__((ext_vector_type(4)));

#define BNRS 0.9999950000374997f   /* 1/sqrt(1+1e-5) */

__device__ __forceinline__ u16 f2bf(float f) {
  unsigned u = __float_as_uint(f);
  u += 0x7fffu + ((u >> 16) & 1u);
  return (u16)(u >> 16);
}
__device__ __forceinline__ float bf2f(u16 h) {
  return __uint_as_float(((unsigned)h) << 16);
}

// async global->LDS DMA, 16B per lane, dest = wave-uniform base + lane*16
__device__ __forceinline__ void glds16(const u16* g, u16* l) {
  __builtin_amdgcn_global_load_lds(
      (const __attribute__((address_space(1))) void*)g,
      (__attribute__((address_space(3))) void*)l, 16, 0, 0);
}

// ---------------- workspace arena layout (bytes) ----------------
// zeroed every launch:
#define OFF_XN     0ull                     /* [128][81][2048] bf16  42,467,328 */
#define OFF_M1     42467328ull              /* [128][81][1024] bf16  21,233,664 */
#define OFF_M2     63700992ull              /* [128][81][512]  bf16  10,616,832 */
#define SZ_M2      10616832ull
// M2 region reused after mask3 (re-zeroed):
#define OFF_MEANX  63700992ull              /* [8][81][2048] bf16  2,654,208 */
#define OFF_XTN    66355200ull              /* [8][81][2048] bf16  2,654,208 */
#define OFF_TH1    69009408ull              /* [8][81][1024] bf16  1,327,104 */
#define OFF_TC1    70336512ull              /* [8][81][1024] bf16  1,327,104 */
#define OFF_HN     71663616ull              /* [8][81][512]  bf16    663,552 */
#define OFF_CST    72327168ull              /* [392][512]    f32     802,816 */
#define OFF_ZXACC  74317824ull              /* [392][2048] f32     3,211,264 */
#define OFF_ATH1   77529088ull              /* [392][1024] f32     1,605,632 */
#define OFF_ATC1   79134720ull
#define OFF_ATH2   80740352ull              /* [392][512] f32        802,816 */
#define OFF_ATC2   81543168ull
#define OFF_FEA    82345984ull              /* [128] f32 */
#define OFF_W      82346496ull              /* [128] f32 */
#define OFF_OUTS   82347008ull              /* [8][512] f32 */
#define Z0_END     82378752ull
// not zeroed (fully overwritten before read):
#define OFF_WA     82378752ull              /* 9*1024*2048 bf16  37,748,736 */
#define OFF_WB     120127488ull             /* 9*512*1024  bf16   9,437,184 */
#define OFF_MX     129564672ull             /* [128][81][2048] bf16 42,467,328 */
// during the mask path the MX region is dead -> split-K f32 accumulators live there:
#define OFF_M1ACC  129564672ull             /* [6272][1024] f32  25,690,112 */
#define OFF_M2ACC  155254784ull             /* [6272][512]  f32  12,845,056 */
#define SZ_MACC    38535168ull
#define OFF_LSTMW  82378752ull              /* 9*2048*2560 bf16 94,371,840 (reuses WA/WB/MX after dead) */
#define OFF_ZPART  176750592ull             /* 8*[392][2048] f32 25,690,112 */
#define ARENA_END  202440704ull

// conv epilogue flags
#define CF_BN    1
#define CF_RELU  2
#define CF_ATOM  4
#define CF_OUTF  8
#define CF_OUTB 16
#define CF_ZOFF 32

// ---------------- implicit-GEMM 3x3 SAME conv, bf16 MFMA ----------------
// Xin: padded NHWC bf16 [nImg][81][Cin] (border rows are zero)
// Wt : [9][Cout?][ldb] bf16, row = output channel, k along input channel
// tile 128(M pix) x 128(N chan), 4 waves, wave = 64x64 via 4x4 16x16x32 MFMAs.
// R5 POST-MORTEM: depth-2 counted-vmcnt gave ZERO per-iter gain vs the naive
// drain (1116 vs 1072 cyc) -> load latency was never exposed (L2 hits hidden
// under ~300cyc compute). The residual is the PER-BARRIER fixed cost
// (~470 cyc rendezvous+vmcnt+issue vs 77 cyc MFMA). Fix: amortize it.
// BK=64: each barrier covers 8 glds16 + 16 ds_read_b128 + 32 MFMA
// (155 MFMA-cyc), halving iterations. Structure = R3's proven 2-buffer
// skeleton (best measured): STAGE(j+1) -> COMPUTE(j) -> __syncthreads.
// Buffers are SEPARATE named arrays (R4 lesson: merged arrays defeat alias
// analysis -> compiler inserts vmcnt(0) before fragment reads).
// K-slice layout: each 8K-u16 buffer = two 4K panels (k-slice 0 / k-slice 1),
// so the glds16 dest mapping (tid*16B within a panel) is unchanged.
// XCD remap (T1): each XCD owns a contiguous (y,z)-panel chunk.
// Read-side XOR swizzle on 16B slots kept from R2 (no cost).
__global__ __launch_bounds__(256)
void k_conv(const u16* __restrict__ Xin, const u16* __restrict__ Wt,
            float* __restrict__ outF, u16* __restrict__ outB,
            float* __restrict__ atomF,
            const float* __restrict__ gamma, const float* __restrict__ beta,
            int M, int Cin, int log2Cin, int ldb, int Cout, int kChunk, int flags)
{
  __shared__ u16 As0[8192], As1[8192];
  __shared__ u16 Bs0[8192], Bs1[8192];
  const int tid = threadIdx.x;

  // ---- XCD-aware tile remap ----
  int bx = blockIdx.x, by = blockIdx.y, bz = blockIdx.z;
  {
    const int gx = gridDim.x, gy = gridDim.y;
    const int P = gy * gridDim.z;          // panels = (y,z) pairs sharing a B-panel
    if ((P & 7) == 0) {
      int flat = bx + gx * (by + gy * bz);
      int xcd = flat & 7, local = flat >> 3, ppx = P >> 3;
      int x = local / ppx, pl = local - x * ppx;
      int panel = xcd * ppx + pl;
      bx = x; by = panel % gy; bz = panel / gy;
    }
  }
  const int m0 = bx*128, n0 = by*128;
  const int row0 = tid >> 2;
  // inverse swizzle on the global source chunk (read-side XOR)
  const int c8 = (((tid & 3) ^ (row0 & 3) ^ ((row0 >> 2) & 3))) * 8;

  long long Abase[2], Bbase[2];
  #pragma unroll
  for (int r = 0; r < 2; ++r) {
    int m = m0 + row0 + r*64; if (m > M-1) m = M-1;   // clamp: safe addr, result discarded
    int img = m / 49, p = m % 49, y = p / 7, xx = p % 7;
    Abase[r] = (long long)(img*81 + y*9 + xx) * Cin + c8;
    Bbase[r] = (long long)(n0 + row0 + r*64) * ldb + c8;
  }
  const long long tapStride = (long long)Cout * ldb;
  const int lane = tid & 63, wave = tid >> 6;
  const int l16 = lane & 15, quad = lane >> 4;
  const int wm = wave & 1, wn = wave >> 1;
  const int fsl = (quad ^ (l16 & 3) ^ ((l16 >> 2) & 3)) * 8;
  const int stg = wave*512;                 // wave-uniform staging base (u16)

  f32x4 acc[4][4];
  #pragma unroll
  for (int i=0;i<4;i++)
    #pragma unroll
    for (int j=0;j<4;j++)
      #pragma unroll
      for (int r=0;r<4;r++) acc[i][j][r] = 0.f;

  const int kStart = bz * kChunk, kEnd = kStart + kChunk;

#define SUBSTAGE(KK, AB, BB) do {                                         \
    int tap_ = (KK) >> log2Cin;                                           \
    int kc_  = (KK) & (Cin - 1);                                          \
    int ty_  = tap_ / 3;                                                  \
    long long off_ = ((long long)(ty_*6 + tap_) << log2Cin) + kc_;        \
    glds16(Xin + Abase[0] + off_, (AB) + stg);                            \
    glds16(Xin + Abase[1] + off_, (AB) + 2048 + stg);                     \
    const u16* wp_ = Wt + (long long)tap_ * tapStride + kc_;              \
    glds16(wp_ + Bbase[0], (BB) + stg);                                   \
    glds16(wp_ + Bbase[1], (BB) + 2048 + stg);                            \
  } while(0)

// stage a BK=64 tile: two K-32 panels at +0 and +4096 u16
#define STAGE64(KK, AB, BB) do {                                          \
    SUBSTAGE((KK), (AB), (BB));                                           \
    SUBSTAGE((KK)+32, (AB)+4096, (BB)+4096);                              \
  } while(0)

// consume a BK=64 tile: 16 ds_read_b128 + 32 MFMA
#define COMPUTE64(AB, BB) do {                                            \
    const u16* Af_ = (AB) + (wm*64 + l16)*32 + fsl;                       \
    const u16* Bf_ = (BB) + (wn*64 + l16)*32 + fsl;                       \
    bf16x8 av[8], bv[8];                                                  \
    _Pragma("unroll")                                                     \
    for (int i=0;i<4;i++) {                                               \
      av[i]   = *(const bf16x8*)(Af_ + i*512);                            \
      av[i+4] = *(const bf16x8*)(Af_ + 4096 + i*512);                     \
      bv[i]   = *(const bf16x8*)(Bf_ + i*512);                            \
      bv[i+4] = *(const bf16x8*)(Bf_ + 4096 + i*512);                     \
    }                                                                     \
    _Pragma("unroll")                                                     \
    for (int i=0;i<4;i++)                                                 \
      _Pragma("unroll")                                                   \
      for (int j=0;j<4;j++) {                                             \
        acc[i][j] = __builtin_amdgcn_mfma_f32_16x16x32_bf16(av[i],   bv[j],   acc[i][j], 0, 0, 0); \
        acc[i][j] = __builtin_amdgcn_mfma_f32_16x16x32_bf16(av[i+4], bv[j+4], acc[i][j], 0, 0, 0); \
      }                                                                   \
  } while(0)

  // prologue
  STAGE64(kStart, As0, Bs0);
  __syncthreads();
  // main loop: iter j covers K-slice [kk, kk+64); buffer parity j&1.
  // guards handle odd iteration counts (e.g. kChunk=576 -> 9 iters).
  for (int kk = kStart; kk < kEnd; kk += 128) {
    if (kk + 64 < kEnd) STAGE64(kk + 64, As1, Bs1);
    COMPUTE64(As0, Bs0);
    __syncthreads();
    if (kk + 128 < kEnd) STAGE64(kk + 128, As0, Bs0);
    if (kk + 64 < kEnd) {
      COMPUTE64(As1, Bs1);
      __syncthreads();
    }
  }
#undef SUBSTAGE
#undef STAGE64
#undef COMPUTE64

  float* outFz = outF;
  if (flags & CF_ZOFF) outFz = outF + (long long)bz * M * Cout;
  #pragma unroll
  for (int i=0;i<4;i++) {
    #pragma unroll
    for (int r=0;r<4;r++) {
      int m = m0 + wm*64 + i*16 + quad*4 + r;
      if (m >= M) continue;
      int img = m / 49, p = m % 49;
      int pp = (p/7 + 1)*9 + (p%7) + 1;
      #pragma unroll
      for (int j=0;j<4;j++) {
        int n = n0 + wn*64 + j*16 + l16;
        float v = acc[i][j][r];
        if (flags & CF_BN)   v = v * (gamma[n]*BNRS) + beta[n];
        if (flags & CF_RELU) v = fmaxf(v, 0.f);
        if (flags & CF_ATOM) atomicAdd(atomF + (long long)m*Cout + n, v);
        if (flags & CF_OUTF) outFz[(long long)m*Cout + n] = v;
        if (flags & CF_OUTB) outB[((long long)img*81 + pp)*Cout + n] = f2bf(v);
      }
    }
  }
}

// W[O][I][3][3] f32 -> Wt[tap][o][i] bf16   (reads 36B/thread contiguous, writes coalesced)
__global__ void k_wtrans(const float* __restrict__ W, u16* __restrict__ Wt, int total) {
  int idx = blockIdx.x*256 + threadIdx.x;
  if (idx >= total) return;
  const float* src = W + (long long)idx*9;
  #pragma unroll
  for (int tap=0; tap<9; ++tap)
    Wt[(long long)tap*total + idx] = f2bf(src[tap]);
}

// input_x (8,2048,16,7,7) f32 -> Xn [128][81][2048] bf16 (interior only)
__global__ void k_transpose(const float* __restrict__ x, u16* __restrict__ Xn) {
  int idx = blockIdx.x*256 + threadIdx.x;   // 8*256*49 = 100352
  int p = idx % 49; int r = idx / 49; int c8 = (r & 255)*8; int b = r >> 8;
  if (b >= 8) return;
  int pp = (p/7 + 1)*9 + (p%7) + 1;
  for (int t=0; t<16; ++t) {
    u16 o[8];
    #pragma unroll
    for (int j=0;j<8;j++)
      o[j] = f2bf(x[((long long)(b*2048 + c8 + j)*16 + t)*49 + p]);
    *(uint4*)&Xn[((long long)(b*16+t)*81 + pp)*2048 + c8] = *(uint4*)o;
  }
}

// mask conv3 (512->1) + sigmoid, one block per output pixel
__global__ void k_mask3(const u16* __restrict__ M2b, const float* __restrict__ w3,
                        float* __restrict__ maskOut) {
  int img = blockIdx.x / 49, p = blockIdx.x % 49;
  int y = p/7, xx = p%7;
  int lane = threadIdx.x;
  float s = 0.f;
  for (int k = lane; k < 4608; k += 64) {
    int tap = k >> 9, c = k & 511;
    int ty = tap/3, tx = tap - ty*3;
    int pp = (y+ty)*9 + xx + tx;
    s += bf2f(M2b[((long long)img*81 + pp)*512 + c]) * w3[c*9 + tap];
  }
  #pragma unroll
  for (int off=32; off>0; off>>=1) s += __shfl_down(s, off, 64);
  if (lane == 0) maskOut[blockIdx.x] = 1.f/(1.f + expf(-s));
}

__global__ void k_losses(const float* __restrict__ mk, float* __restrict__ dout) {
  __shared__ float s1[256], s2[256];
  int tid = threadIdx.x;
  float tv = 0.f, ct = 0.f;
  for (int i = tid; i < 128*7*6; i += 256) {          // horizontal diffs
    int img = i / 42, r = i % 42, y = r / 6, xx = r % 6;
    int base = img*49 + y*7 + xx;
    tv += fabsf(mk[base+1] - mk[base]);
  }
  for (int i = tid; i < 128*6*7; i += 256) {          // vertical diffs
    int img = i / 42, r = i % 42, y = r / 7, xx = r % 7;
    int base = img*49 + y*7 + xx;
    tv += fabsf(mk[base+7] - mk[base]);
  }
  for (int i = tid; i < 6272; i += 256) {
    float v = mk[i];
    ct += (v < 0.5f ? v : 0.f) - (v > 0.5f ? v : 0.f);
  }
  s1[tid] = tv; s2[tid] = ct; __syncthreads();
  for (int off=128; off>0; off>>=1) {
    if (tid < off) { s1[tid]+=s1[tid+off]; s2[tid]+=s2[tid+off]; }
    __syncthreads();
  }
  if (tid==0) { dout[6424] = 1e-5f * s1[0]; dout[6425] = (1e-4f*0.5f/8.f) * s2[0]; }
}

// mx = mask*x (bf16, padded NHWC) and mean over T
__global__ void k_mx(const float* __restrict__ x, const float* __restrict__ mk,
                     u16* __restrict__ mxn, u16* __restrict__ meanx) {
  int idx = blockIdx.x*256 + threadIdx.x;
  int p = idx % 49; int r = idx / 49; int c8 = (r & 255)*8; int b = r >> 8;
  if (b >= 8) return;
  int pp = (p/7+1)*9 + (p%7) + 1;
  float macc[8] = {0,0,0,0,0,0,0,0};
  for (int t=0;t<16;++t) {
    float mval = mk[(b*16+t)*49 + p];
    u16 o[8];
    #pragma unroll
    for (int j=0;j<8;j++) {
      float v = x[((long long)(b*2048 + c8 + j)*16 + t)*49 + p] * mval;
      o[j] = f2bf(v); macc[j] += v;
    }
    *(uint4*)&mxn[((long long)(b*16+t)*81 + pp)*2048 + c8] = *(uint4*)o;
  }
  u16 o2[8];
  #pragma unroll
  for (int j=0;j<8;j++) o2[j] = f2bf(macc[j] * (1.f/16.f));
  *(uint4*)&meanx[((long long)b*81 + pp)*2048 + c8] = *(uint4*)o2;
}

// att_fea[img] = (1/49) * sum_{p,c} mx * att_fw[c]
__global__ void k_att(const u16* __restrict__ mxn, const float* __restrict__ fw,
                      float* __restrict__ fea) {
  __shared__ float red[256];
  int img = blockIdx.x, tid = threadIdx.x;
  const u16* base = mxn + (long long)img*81*2048;
  float s = 0.f;
  for (int k = tid; k < 49*2048; k += 256) {
    int p = k >> 11, c = k & 2047;
    int pp = (p/7+1)*9 + (p%7) + 1;
    s += bf2f(base[(long long)pp*2048 + c]) * fw[c];
  }
  red[tid] = s; __syncthreads();
  for (int off=128; off>0; off>>=1) { if (tid<off) red[tid]+=red[tid+off]; __syncthreads(); }
  if (tid==0) fea[img] = red[0] * (1.f/49.f);
}

// softmax over T (att_h is (B,1): shift-invariant, w identical every step)
__global__ void k_softmax(const float* __restrict__ fea, float* __restrict__ w,
                          float* __restrict__ doutW) {
  int b = threadIdx.x;
  if (b >= 8) return;
  float mx = -1e30f;
  for (int t=0;t<16;t++) mx = fmaxf(mx, fea[b*16+t]);
  float e[16], s = 0.f;
  for (int t=0;t<16;t++) { e[t] = expf(fea[b*16+t]-mx); s += e[t]; }
  float inv = 1.f/s;
  for (int t=0;t<16;t++) { float v = e[t]*inv; w[b*16+t] = v; doutW[b*16+t] = v; }
}

// xt = sum_t w[b,t]*mx[b,t]  (bf16, padded NHWC)
__global__ void k_xt(const u16* __restrict__ mxn, const float* __restrict__ w,
                     u16* __restrict__ xtn) {
  int idx = blockIdx.x*256 + threadIdx.x;
  int c8 = (idx & 255)*8; int r = idx >> 8; int p = r % 49; int b = r / 49;
  if (b >= 8) return;
  int pp = (p/7+1)*9 + (p%7)+1;
  float a[8] = {0,0,0,0,0,0,0,0};
  for (int t=0;t<16;t++) {
    float wt = w[b*16+t];
    uint4 raw = *(const uint4*)&mxn[((long long)(b*16+t)*81 + pp)*2048 + c8];
    const u16* h = (const u16*)&raw;
    #pragma unroll
    for (int j=0;j<8;j++) a[j] += wt * bf2f(h[j]);
  }
  u16 o[8];
  #pragma unroll
  for (int j=0;j<8;j++) o[j] = f2bf(a[j]);
  *(uint4*)&xtn[((long long)b*81+pp)*2048 + c8] = *(uint4*)o;
}

// split-K atomic accum -> BN+ReLU -> bf16 padded (borders zeroed) and/or f32 compact
__global__ void k_finalize(const float* __restrict__ acc, const float* __restrict__ bn,
                           u16* __restrict__ outB, float* __restrict__ outF,
                           int C, int nImg) {
  int idx = blockIdx.x*256 + threadIdx.x;
  int total = nImg*81*C;
  if (idx >= total) return;
  int c = idx % C; int r = idx / C; int pp = r % 81; int img = r / 81;
  int py = pp/9, px = pp%9;
  bool inter = (py>=1 && py<=7 && px>=1 && px<=7);
  float v = 0.f;
  int m = img*49 + (py-1)*7 + (px-1);
  if (inter) {
    v = acc[(long long)m*C + c];
    v = v*(bn[c]*BNRS) + bn[C+c];
    v = fmaxf(v, 0.f);
  }
  if (outB) outB[idx] = f2bf(v);
  if (outF && inter) outF[(long long)m*C + c] = v;
}

// LSTM gates: z = zx + lstm_b + sum_s zpart[s]; update c,h; accumulate outs mean
__global__ void k_gate(const float* __restrict__ zx, const float* __restrict__ zp,
                       const float* __restrict__ lb, float* __restrict__ cst,
                       u16* __restrict__ hn, float* __restrict__ outs) {
  int idx = blockIdx.x*256 + threadIdx.x;
  if (idx >= 392*512) return;
  int c = idx & 511; int m = idx >> 9;
  int b = m / 49, p = m % 49;
  int pp = (p/7+1)*9 + (p%7)+1;
  const float* zr = zx + (long long)m*2048;
  float zi = zr[c]        + lb[c];
  float zf = zr[c+512]    + lb[c+512];
  float zo = zr[c+1024]   + lb[c+1024];
  float zg = zr[c+1536]   + lb[c+1536];
  #pragma unroll
  for (int s=0;s<8;s++) {
    const float* q = zp + ((long long)s*392 + m)*2048;
    zi += q[c]; zf += q[c+512]; zo += q[c+1024]; zg += q[c+1536];
  }
  float si = 1.f/(1.f+expf(-zi));
  float sf = 1.f/(1.f+expf(-zf));
  float so = 1.f/(1.f+expf(-zo));
  float cn = sf*cst[idx] + si*tanhf(zg);
  float h  = so*tanhf(cn);
  cst[idx] = cn;
  hn[((long long)b*81 + pp)*512 + c] = f2bf(h);
  atomicAdd(outs + b*512 + c, h*(1.f/784.f));   // /49 pixels /16 steps
}

__global__ void k_fc(const float* __restrict__ outs, const float* __restrict__ fcw,
                     const float* __restrict__ fcb, float* __restrict__ dout) {
  int t = threadIdx.x;
  if (t >= 24) return;
  int b = t / 3, j = t % 3;
  float s = fcb[j];
  for (int c=0;c<512;c++) s += outs[b*512+c]*fcw[j*512+c];
  dout[b*3+j] = s;
}

extern "C" void kernel_launch(void* const* d_in, const int* in_sizes, int n_in,
                              void* d_out, int out_size, void* d_ws, size_t ws_size,
                              hipStream_t stream) {
  (void)in_sizes; (void)n_in; (void)out_size;
  const float* x        = (const float*)d_in[0];
  const float* mask_w1  = (const float*)d_in[1];
  const float* mask_bn1 = (const float*)d_in[2];
  const float* mask_w2  = (const float*)d_in[3];
  const float* mask_bn2 = (const float*)d_in[4];
  const float* mask_w3  = (const float*)d_in[5];
  const float* h0_w1    = (const float*)d_in[6];
  const float* h0_bn1   = (const float*)d_in[7];
  const float* h0_w2    = (const float*)d_in[8];
  const float* h0_bn2   = (const float*)d_in[9];
  const float* c0_w1    = (const float*)d_in[10];
  const float* c0_bn1   = (const float*)d_in[11];
  const float* c0_w2    = (const float*)d_in[12];
  const float* c0_bn2   = (const float*)d_in[13];
  const float* att_fw   = (const float*)d_in[14];
  // d_in[15] = att_hw: mathematically irrelevant (softmax shift-invariance)
  const float* lstm_w   = (const float*)d_in[16];
  const float* lstm_b   = (const float*)d_in[17];
  const float* fc_w     = (const float*)d_in[18];
  const float* fc_b     = (const float*)d_in[19];
  float* dout = (float*)d_out;
  char* ws = (char*)d_ws;
  if (ws_size < ARENA_END) return;

  u16* XN    = (u16*)(ws + OFF_XN);
  u16* M1b   = (u16*)(ws + OFF_M1);
  u16* M2b   = (u16*)(ws + OFF_M2);
  u16* MEANX = (u16*)(ws + OFF_MEANX);
  u16* XTN   = (u16*)(ws + OFF_XTN);
  u16* TH1   = (u16*)(ws + OFF_TH1);
  u16* TC1   = (u16*)(ws + OFF_TC1);
  u16* HN    = (u16*)(ws + OFF_HN);
  float* CST   = (float*)(ws + OFF_CST);
  float* ZXACC = (float*)(ws + OFF_ZXACC);
  float* ATH1  = (float*)(ws + OFF_ATH1);
  float* ATC1  = (float*)(ws + OFF_ATC1);
  float* ATH2  = (float*)(ws + OFF_ATH2);
  float* ATC2  = (float*)(ws + OFF_ATC2);
  float* FEA   = (float*)(ws + OFF_FEA);
  float* Wbuf  = (float*)(ws + OFF_W);
  float* OUTS  = (float*)(ws + OFF_OUTS);
  u16* WA    = (u16*)(ws + OFF_WA);
  u16* WB    = (u16*)(ws + OFF_WB);
  u16* MX    = (u16*)(ws + OFF_MX);
  u16* LSTMW = (u16*)(ws + OFF_LSTMW);
  float* ZPART = (float*)(ws + OFF_ZPART);
  float* M1ACC = (float*)(ws + OFF_M1ACC);
  float* M2ACC = (float*)(ws + OFF_M2ACC);

  hipMemsetAsync(ws, 0, (size_t)Z0_END, stream);
  hipMemsetAsync(ws + OFF_M1ACC, 0, (size_t)SZ_MACC, stream);  // split-K accumulators

  // ---- mask path (split-K z=4) ----
  k_wtrans<<<8192, 256, 0, stream>>>(mask_w1, WA, 1024*2048);
  k_wtrans<<<2048, 256, 0, stream>>>(mask_w2, WB, 512*1024);
  k_transpose<<<392, 256, 0, stream>>>(x, XN);
  k_conv<<<dim3(49,8,4),256,0,stream>>>(XN, WA, nullptr, nullptr, M1ACC,
      nullptr, nullptr, 6272, 2048, 11, 2048, 1024, 4608, CF_ATOM);
  k_finalize<<<41472, 256, 0, stream>>>(M1ACC, mask_bn1, M1b, nullptr, 1024, 128);
  k_conv<<<dim3(49,4,4),256,0,stream>>>(M1b, WB, nullptr, nullptr, M2ACC,
      nullptr, nullptr, 6272, 1024, 10, 1024, 512, 2304, CF_ATOM);
  k_finalize<<<20736, 256, 0, stream>>>(M2ACC, mask_bn2, M2b, nullptr, 512, 128);
  k_mask3<<<6272, 64, 0, stream>>>(M2b, mask_w3, dout+152);
  k_losses<<<1, 256, 0, stream>>>(dout+152, dout);

  // ---- attention-weighted features ----
  hipMemsetAsync(ws + OFF_M2, 0, (size_t)SZ_M2, stream);   // re-zero reused region (borders)
  k_mx<<<392, 256, 0, stream>>>(x, dout+152, MX, MEANX);
  k_att<<<128, 256, 0, stream>>>(MX, att_fw, FEA);
  k_softmax<<<1, 64, 0, stream>>>(FEA, Wbuf, dout+24);
  k_xt<<<392, 256, 0, stream>>>(MX, Wbuf, XTN);

  // ---- h0 path (z=16) ----
  k_wtrans<<<8192, 256, 0, stream>>>(h0_w1, WA, 1024*2048);
  k_wtrans<<<2048, 256, 0, stream>>>(h0_w2, WB, 512*1024);
  k_conv<<<dim3(4,8,16),256,0,stream>>>(MEANX, WA, nullptr, nullptr, ATH1,
      nullptr, nullptr, 392, 2048, 11, 2048, 1024, 1152, CF_ATOM);
  k_finalize<<<2592, 256, 0, stream>>>(ATH1, h0_bn1, TH1, nullptr, 1024, 8);
  k_conv<<<dim3(4,4,16),256,0,stream>>>(TH1, WB, nullptr, nullptr, ATH2,
      nullptr, nullptr, 392, 1024, 10, 1024, 512, 576, CF_ATOM);
  k_finalize<<<1296, 256, 0, stream>>>(ATH2, h0_bn2, HN, nullptr, 512, 8);

  // ---- c0 path (z=16) ----
  k_wtrans<<<8192, 256, 0, stream>>>(c0_w1, WA, 1024*2048);
  k_wtrans<<<2048, 256, 0, stream>>>(c0_w2, WB, 512*1024);
  k_conv<<<dim3(4,8,16),256,0,stream>>>(MEANX, WA, nullptr, nullptr, ATC1,
      nullptr, nullptr, 392, 2048, 11, 2048, 1024, 1152, CF_ATOM);
  k_finalize<<<2592, 256, 0, stream>>>(ATC1, c0_bn1, TC1, nullptr, 1024, 8);
  k_conv<<<dim3(4,4,16),256,0,stream>>>(TC1, WB, nullptr, nullptr, ATC2,
      nullptr, nullptr, 392, 1024, 10, 1024, 512, 576, CF_ATOM);
  k_finalize<<<1296, 256, 0, stream>>>(ATC2, c0_bn2, nullptr, CST, 512, 8);

  // ---- LSTM: zx precomputed once (w constant across steps), z=16 ----
  k_wtrans<<<20480, 256, 0, stream>>>(lstm_w, LSTMW, 2048*2560);
  k_conv<<<dim3(4,16,16),256,0,stream>>>(XTN, LSTMW, nullptr, nullptr, ZXACC,
      nullptr, nullptr, 392, 2048, 11, 2560, 2048, 1152, CF_ATOM);
  for (int step = 0; step < 16; ++step) {
    k_conv<<<dim3(4,16,8),256,0,stream>>>(HN, LSTMW+2048, ZPART, nullptr, nullptr,
        nullptr, nullptr, 392, 512, 9, 2560, 2048, 576, CF_OUTF|CF_ZOFF);
    k_gate<<<784, 256, 0, stream>>>(ZXACC, ZPART, lstm_b, CST, HN, OUTS);
  }
  k_fc<<<1, 64, 0, stream>>>(OUTS, fc_w, fc_b, dout);
}